// Round 8
// baseline (247.749 us; speedup 1.0000x reference)
//
#include <hip/hip_runtime.h>
#include <cstdint>

#define B_ 8
#define T_ 16
#define N_ 2048
#define CIN_ 2
#define H_ 64
#define COUT_ 64
#define KT_ 3
#define E_ 32768
#define T1_ 14
#define T2_ 12
#define G_ (B_*T1_)   // 112 graphs
#define GS_ (G_*H_)   // 7168: per-node stride in interleaved layout

typedef __attribute__((ext_vector_type(8))) short bf16x8;
typedef __attribute__((ext_vector_type(4))) float f32x4;
typedef unsigned short ushort_;
typedef __attribute__((ext_vector_type(8))) unsigned short u16x8;

__device__ __forceinline__ float sigmoidf_(float x){ return 1.f/(1.f+expf(-x)); }
__device__ __forceinline__ int rfl_(int x){ return __builtin_amdgcn_readfirstlane(x); }

__device__ __forceinline__ ushort_ f2b(float x){
  union {float f; uint32_t u;} v; v.f = x;
  uint32_t r = (v.u + 0x7FFFu + ((v.u>>16)&1u)) >> 16;
  return (ushort_)r;
}
__device__ __forceinline__ float b2f(ushort_ x){
  union {uint32_t u; float f;} v; v.u = ((uint32_t)x)<<16;
  return v.f;
}

// ---------------- CSR build: ONE block, LDS histogram + scan + fill ----------------
__global__ __launch_bounds__(1024) void k_csr(
    const int* __restrict__ src, const int* __restrict__ dst,
    const float* __restrict__ ew, int* __restrict__ offs_g,
    int2* __restrict__ epack){
  __shared__ float degf[N_];   // -> dis in place
  __shared__ int   cnts[N_];
  __shared__ int   offss[N_];
  __shared__ int   fillc[N_];
  __shared__ int   psum[1024];
  int tid = threadIdx.x;
  for(int i=tid;i<N_;i+=1024){ degf[i]=0.f; cnts[i]=0; fillc[i]=0; }
  __syncthreads();
  for(int e=tid;e<E_;e+=1024){
    int s=src[e], d=dst[e];
    float w = (s==d)?0.f:ew[e];
    atomicAdd(&degf[s], w);
    atomicAdd(&cnts[d], 1);
  }
  __syncthreads();
  for(int i=tid;i<N_;i+=1024){ float dg=degf[i]; degf[i] = dg>0.f? rsqrtf(dg):0.f; }
  int b0 = cnts[tid*2], b1 = cnts[tid*2+1];
  psum[tid] = b0+b1;
  __syncthreads();
  for(int ofs=1; ofs<1024; ofs<<=1){
    int t = (tid>=ofs)? psum[tid-ofs] : 0;
    __syncthreads();
    psum[tid] += t;
    __syncthreads();
  }
  int ebase = (tid==0)?0:psum[tid-1];
  offss[tid*2]   = ebase;
  offss[tid*2+1] = ebase + b0;
  offs_g[tid*2]   = ebase;
  offs_g[tid*2+1] = ebase + b0;
  if(tid==1023) offs_g[N_] = psum[1023];
  __syncthreads();
  for(int e=tid;e<E_;e+=1024){
    int s=src[e], d=dst[e];
    float w=(s==d)?0.f:ew[e];
    float wn = -degf[s]*w*degf[d];
    int pos = offss[d] + atomicAdd(&fillc[d],1);
    epack[pos] = make_int2(s, __float_as_int(wn));
  }
}

// ---- weight prepack (merged): blocks 0..5 cheb (baked W0-W2|W1|2W2), 6..17 conv2 ----
__global__ void k_prep(const float* __restrict__ cw, const float* __restrict__ w2,
                       ushort_* __restrict__ Bp, ushort_* __restrict__ Bp2){
  int bi = blockIdx.x; int tid = threadIdx.x;
  if(bi < 6){
    int i = bi*256 + tid;            // 6*4*64 = 1536
    int lane = i & 63; int cn = i >> 6; int c = cn >> 2; int n = cn & 3;
    #pragma unroll
    for(int j=0;j<8;j++){
      int k = c*32 + (lane>>4)*8 + j;   // 0..191
      int h = k & 63; int m = k >> 6;
      int col = n*16 + (lane&15);
      float v;
      if(m == 0)      v = cw[(size_t)h*64 + col] - cw[(size_t)(128+h)*64 + col];
      else if(m == 1) v = cw[(size_t)(64+h)*64 + col];
      else            v = 2.f*cw[(size_t)(128+h)*64 + col];
      Bp[(size_t)i*8 + j] = f2b(v);
    }
  } else {
    int i = (bi-6)*256 + tid;        // 6*8*64 = 3072
    int lane = i & 63; int cn = i >> 6; int c = cn >> 3; int n = cn & 7;
    #pragma unroll
    for(int j=0;j<8;j++){
      int k = c*32 + (lane>>4)*8 + j;
      int co = n*16 + (lane&15);
      int kt = k >> 6, ci = k & 63;
      Bp2[(size_t)i*8 + j] = f2b(w2[(size_t)co*192 + ci*3 + kt]);
    }
  }
}

// ---------------- temporal conv 1 + GLU -> bf16, interleaved [n][g][c] ----------------
__global__ void k_conv1(const float* __restrict__ X, const float* __restrict__ w1,
                        const float* __restrict__ b1, ushort_* __restrict__ t0){
  int wv = rfl_(blockIdx.x*4 + (threadIdx.x>>6));
  int lane = threadIdx.x & 63;
  int nb = wv % (N_/8); int bt = wv / (N_/8); int b = bt / T1_; int t = bt % T1_;
  int n0 = nb*8;
  const float* Xp = X + ((size_t)((b*T_ + t)*N_ + n0))*CIN_;
  float wp[6], wq[6];
  #pragma unroll
  for(int k=0;k<6;k++){
    wp[k] = w1[ lane      *6 + k];   // k = ci*3 + kt
    wq[k] = w1[(lane+H_)*6 + k];
  }
  float bp = b1[lane], bq = b1[lane+H_];
  #pragma unroll
  for(int j=0;j<8;j++){
    float yp = bp, yq = bq;
    #pragma unroll
    for(int kt=0;kt<KT_;kt++)
      #pragma unroll
      for(int ci=0;ci<CIN_;ci++){
        float x = Xp[kt*(N_*CIN_) + j*CIN_ + ci];
        yp += x * wp[ci*3+kt];
        yq += x * wq[ci*3+kt];
      }
    float xin = (lane < CIN_) ? Xp[2*(N_*CIN_) + j*CIN_ + lane] : 0.f;
    t0[(size_t)(n0+j)*GS_ + (size_t)bt*H_ + lane] = f2b((yp + xin) * sigmoidf_(yq));
  }
}

// ---------------- SpMM interleaved: tx1 = L t0. 8 graphs/wave, 16B gathers, XCD-swizzled ----
__global__ void k_spmm3(const ushort_* __restrict__ zin, ushort_* __restrict__ out,
                        const int* __restrict__ offs, const int2* __restrict__ epack){
  int lane = threadIdx.x & 63;
  int wv = threadIdx.x >> 6;
  int bid = blockIdx.x;                 // 14*512 = 7168
  int work = (bid & 7)*896 + (bid >> 3);
  int gg = work >> 9;                   // 0..13
  int dblk = work & 511;
  int d = dblk*4 + wv;
  int e0 = offs[d], e1 = offs[d+1];
  size_t lo = (size_t)(gg*8)*H_ + lane*8;
  const ushort_* zb = zin + lo;
  float ac[8] = {};
  #pragma unroll 2
  for(int i=e0;i<e1;i++){
    int2 e = epack[i];
    float w = __int_as_float(e.y);
    u16x8 zv = *(const u16x8*)(zb + (size_t)e.x*GS_);
    #pragma unroll
    for(int j=0;j<8;j++) ac[j] += w*b2f(zv[j]);
  }
  u16x8 ov;
  #pragma unroll
  for(int j=0;j<8;j++) ov[j] = f2b(ac[j]);
  *(u16x8*)(out + (size_t)d*GS_ + lo) = ov;
}

// ---------------- cheb fused: y2 gather (spmm2) + MFMA GEMM, LDS-staged baked B ----------------
// tg = relu(bias + t0*(W0-W2) + tx1*W1 + (L tx1)*(2W2))
__global__ __launch_bounds__(256) void k_cheb_fused(
    const ushort_* __restrict__ t0, const ushort_* __restrict__ tx1,
    const ushort_* __restrict__ Bp, const float* __restrict__ bias,
    const int* __restrict__ offs, const int2* __restrict__ epack,
    ushort_* __restrict__ tg){
  __shared__ ushort_ lb[6*4*64*8];   // 24 KB
  int tid = threadIdx.x;
  #pragma unroll
  for(int i=0;i<6;i++)
    *(u16x8*)(lb + i*2048 + tid*8) = *(const u16x8*)(Bp + i*2048 + tid*8);
  __syncthreads();
  int lane = tid & 63;
  int wv = tid >> 6;
  int bid = blockIdx.x;                  // 1792 = 8 XCD * 224
  int work = (bid & 7)*224 + (bid >> 3); // all 16 blocks of a graph on one XCD
  int g = work >> 4;
  int row0 = (work & 15)*128 + wv*32;
  int ra = row0 + (lane&15);
  int e4 = (lane>>4)*8;
  bf16x8 a[2][6];
  // A fragments c=0..3 from t0/tx1 (direct loads)
  #pragma unroll
  for(int c=0;c<4;c++){
    const ushort_* s = (c>>1)==0 ? t0 : tx1;
    int eoff = (c&1)*32 + e4;
    const ushort_* sb = s + (size_t)g*H_ + eoff;
    a[0][c] = *(const bf16x8*)(sb + (size_t)ra*GS_);
    a[1][c] = *(const bf16x8*)(sb + (size_t)(ra+16)*GS_);
  }
  // A fragments c=4,5: y2 = L tx1 computed in-register by per-lane edge gather
  const ushort_* zb = tx1 + (size_t)g*H_;
  #pragma unroll
  for(int rg=0;rg<2;rg++){
    int r = ra + rg*16;
    int e0 = offs[r], e1 = offs[r+1];
    float a4[8] = {}, a5[8] = {};
    for(int i=e0;i<e1;i++){
      int2 e = epack[i];
      float w = __int_as_float(e.y);
      const ushort_* zr = zb + (size_t)e.x*GS_;
      u16x8 z4 = *(const u16x8*)(zr + e4);
      u16x8 z5 = *(const u16x8*)(zr + 32 + e4);
      #pragma unroll
      for(int j=0;j<8;j++){ a4[j] += w*b2f(z4[j]); a5[j] += w*b2f(z5[j]); }
    }
    bf16x8 p4, p5;
    #pragma unroll
    for(int j=0;j<8;j++){ p4[j] = (short)f2b(a4[j]); p5[j] = (short)f2b(a5[j]); }
    a[rg][4] = p4; a[rg][5] = p5;
  }
  f32x4 acc[2][4] = {};
  #pragma unroll
  for(int c=0;c<6;c++){
    #pragma unroll
    for(int n=0;n<4;n++){
      bf16x8 bfr = *(const bf16x8*)(lb + ((c*4+n)*64 + lane)*8);
      acc[0][n] = __builtin_amdgcn_mfma_f32_16x16x32_bf16(a[0][c], bfr, acc[0][n], 0,0,0);
      acc[1][n] = __builtin_amdgcn_mfma_f32_16x16x32_bf16(a[1][c], bfr, acc[1][n], 0,0,0);
    }
  }
  #pragma unroll
  for(int rg=0; rg<2; rg++)
    #pragma unroll
    for(int n=0;n<4;n++){
      int col = n*16 + (lane&15);
      float bv = bias[col];
      #pragma unroll
      for(int r=0;r<4;r++){
        int row = row0 + rg*16 + (lane>>4)*4 + r;
        float v = fmaxf(acc[rg][n][r] + bv, 0.f);
        tg[(size_t)(g*N_+row)*H_ + col] = f2b(v);
      }
    }
}

// ---------------- conv2 via MFMA (LDS-staged B, 32 rows/wave) ----------------
__global__ __launch_bounds__(256) void k_conv2_mfma(
    const ushort_* __restrict__ tg, const ushort_* __restrict__ Bp2,
    const float* __restrict__ b2, float* __restrict__ out){
  __shared__ ushort_ lb[6*8*64*8];  // 48 KB
  int tid = threadIdx.x;
  #pragma unroll
  for(int i=0;i<12;i++)
    *(u16x8*)(lb + i*2048 + tid*8) = *(const u16x8*)(Bp2 + i*2048 + tid*8);
  __syncthreads();
  int lane = tid & 63;
  int wv = tid >> 6;
  int blk = blockIdx.x;          // 96*16
  int bt = blk >> 4; int nblk = blk & 15;
  int b = bt / T2_, t = bt % T2_;
  int n0 = nblk*128 + wv*32;
  const ushort_* base = tg + (size_t)(b*T1_ + t)*N_*H_;
  int ra = n0 + (lane&15);
  f32x4 acc[2][8] = {};
  #pragma unroll
  for(int c=0;c<6;c++){
    const ushort_* s = base + (size_t)(c>>1)*N_*H_;
    int eoff = (c&1)*32 + (lane>>4)*8;
    bf16x8 a0 = *(const bf16x8*)(s + (size_t)ra*H_ + eoff);
    bf16x8 a1 = *(const bf16x8*)(s + (size_t)(ra+16)*H_ + eoff);
    #pragma unroll
    for(int n=0;n<8;n++){
      bf16x8 bfr = *(const bf16x8*)(lb + ((c*8+n)*64 + lane)*8);
      acc[0][n] = __builtin_amdgcn_mfma_f32_16x16x32_bf16(a0, bfr, acc[0][n], 0,0,0);
      acc[1][n] = __builtin_amdgcn_mfma_f32_16x16x32_bf16(a1, bfr, acc[1][n], 0,0,0);
    }
  }
  const ushort_* xslab = base + (size_t)2*N_*H_;
  float* ob = out + (size_t)(b*T2_ + t)*N_*H_;
  #pragma unroll
  for(int rg=0;rg<2;rg++)
    #pragma unroll
    for(int n=0;n<4;n++){
      int col = n*16 + (lane&15);
      float bp = b2[col], bq = b2[col+COUT_];
      #pragma unroll
      for(int r=0;r<4;r++){
        int row = n0 + rg*16 + (lane>>4)*4 + r;
        float xin = b2f(xslab[(size_t)row*H_ + col]);
        float p = acc[rg][n][r] + bp + xin;
        float q = acc[rg][n+4][r] + bq;
        ob[(size_t)row*H_ + col] = p * sigmoidf_(q);
      }
    }
}

extern "C" void kernel_launch(void* const* d_in, const int* in_sizes, int n_in,
                              void* d_out, int out_size, void* d_ws, size_t ws_size,
                              hipStream_t stream){
  (void)in_sizes; (void)n_in; (void)out_size; (void)ws_size;
  const float* X  = (const float*)d_in[0];
  const int*   ei = (const int*)d_in[1];
  const float* ew = (const float*)d_in[2];
  const float* w1 = (const float*)d_in[3];
  const float* b1 = (const float*)d_in[4];
  const float* cw = (const float*)d_in[5];
  const float* cb = (const float*)d_in[6];
  const float* w2 = (const float*)d_in[7];
  const float* b2 = (const float*)d_in[8];
  float* out = (float*)d_out;

  char* ws = (char*)d_ws;
  const size_t BUF = (size_t)G_*N_*H_*sizeof(ushort_); // 29,360,128 B
  ushort_* t0  = (ushort_*)(ws);
  ushort_* tx1 = (ushort_*)(ws + BUF);
  ushort_* tg  = (ushort_*)(ws + 2*BUF);
  char* sm = ws + 3*BUF;
  int*   offs  = (int*)  (sm);               // 8448
  int2*  epack = (int2*) (sm + 8448);        // 262144
  ushort_* Bp  = (ushort_*)(sm + 8448 + 262144);          // 24576
  ushort_* Bp2 = (ushort_*)(sm + 8448 + 262144 + 24576);  // 49152

  const int* src = ei;
  const int* dst = ei + E_;

  k_csr <<<1, 1024, 0, stream>>>(src, dst, ew, offs, epack);
  k_prep<<<18, 256, 0, stream>>>(cw, w2, Bp, Bp2);

  // stage 1: temporal conv1 + GLU -> t0 (bf16, interleaved)
  k_conv1<<<(G_*N_/8)/4, 256, 0, stream>>>(X, w1, b1, t0);

  // tx1 = L t0
  k_spmm3<<<14*512, 256, 0, stream>>>(t0, tx1, offs, epack);

  // tg = relu(bias + t0*(W0-W2) + tx1*W1 + (L tx1)*(2W2))  (fused spmm2 + MFMA)
  k_cheb_fused<<<G_*16, 256, 0, stream>>>(t0, tx1, Bp, cb, offs, epack, tg);

  // stage 3: temporal conv2 + GLU -> out   (MFMA, LDS B)
  k_conv2_mfma<<<(B_*T2_)*16, 256, 0, stream>>>(tg, Bp2, b2, out);
}

// Round 9
// 204.932 us; speedup vs baseline: 1.2089x; 1.2089x over previous
//
#include <hip/hip_runtime.h>
#include <cstdint>

#define B_ 8
#define T_ 16
#define N_ 2048
#define CIN_ 2
#define H_ 64
#define COUT_ 64
#define KT_ 3
#define E_ 32768
#define T1_ 14
#define T2_ 12
#define G_ (B_*T1_)   // 112 graphs

typedef __attribute__((ext_vector_type(8))) short bf16x8;
typedef __attribute__((ext_vector_type(4))) float f32x4;
typedef unsigned short ushort_;
typedef __attribute__((ext_vector_type(8))) unsigned short u16x8;

__device__ __forceinline__ float sigmoidf_(float x){ return 1.f/(1.f+expf(-x)); }
__device__ __forceinline__ int rfl_(int x){ return __builtin_amdgcn_readfirstlane(x); }

__device__ __forceinline__ ushort_ f2b(float x){
  union {float f; uint32_t u;} v; v.f = x;
  uint32_t r = (v.u + 0x7FFFu + ((v.u>>16)&1u)) >> 16;
  return (ushort_)r;
}
__device__ __forceinline__ float b2f(ushort_ x){
  union {uint32_t u; float f;} v; v.u = ((uint32_t)x)<<16;
  return v.f;
}

// ---------------- CSR build: ONE block, LDS histogram + scan + fill ----------------
__global__ __launch_bounds__(1024) void k_csr(
    const int* __restrict__ src, const int* __restrict__ dst,
    const float* __restrict__ ew, int* __restrict__ offs_g,
    int2* __restrict__ epack){
  __shared__ float degf[N_];   // -> dis in place
  __shared__ int   cnts[N_];
  __shared__ int   offss[N_];
  __shared__ int   fillc[N_];
  __shared__ int   psum[1024];
  int tid = threadIdx.x;
  for(int i=tid;i<N_;i+=1024){ degf[i]=0.f; cnts[i]=0; fillc[i]=0; }
  __syncthreads();
  for(int e=tid;e<E_;e+=1024){
    int s=src[e], d=dst[e];
    float w = (s==d)?0.f:ew[e];
    atomicAdd(&degf[s], w);
    atomicAdd(&cnts[d], 1);
  }
  __syncthreads();
  for(int i=tid;i<N_;i+=1024){ float dg=degf[i]; degf[i] = dg>0.f? rsqrtf(dg):0.f; }
  int b0 = cnts[tid*2], b1 = cnts[tid*2+1];
  psum[tid] = b0+b1;
  __syncthreads();
  for(int ofs=1; ofs<1024; ofs<<=1){
    int t = (tid>=ofs)? psum[tid-ofs] : 0;
    __syncthreads();
    psum[tid] += t;
    __syncthreads();
  }
  int ebase = (tid==0)?0:psum[tid-1];
  offss[tid*2]   = ebase;
  offss[tid*2+1] = ebase + b0;
  offs_g[tid*2]   = ebase;
  offs_g[tid*2+1] = ebase + b0;
  if(tid==1023) offs_g[N_] = psum[1023];
  __syncthreads();
  for(int e=tid;e<E_;e+=1024){
    int s=src[e], d=dst[e];
    float w=(s==d)?0.f:ew[e];
    float wn = -degf[s]*w*degf[d];
    int pos = offss[d] + atomicAdd(&fillc[d],1);
    epack[pos] = make_int2(s, __float_as_int(wn));
  }
}

// ---- weight prepack (merged): blocks 0..5 cheb (baked W0-W2|W1|2W2), 6..17 conv2 ----
__global__ void k_prep(const float* __restrict__ cw, const float* __restrict__ w2,
                       ushort_* __restrict__ Bp, ushort_* __restrict__ Bp2){
  int bi = blockIdx.x; int tid = threadIdx.x;
  if(bi < 6){
    int i = bi*256 + tid;            // 6*4*64 = 1536
    int lane = i & 63; int cn = i >> 6; int c = cn >> 2; int n = cn & 3;
    #pragma unroll
    for(int j=0;j<8;j++){
      int k = c*32 + (lane>>4)*8 + j;   // 0..191
      int h = k & 63; int m = k >> 6;
      int col = n*16 + (lane&15);
      float v;
      if(m == 0)      v = cw[(size_t)h*64 + col] - cw[(size_t)(128+h)*64 + col];
      else if(m == 1) v = cw[(size_t)(64+h)*64 + col];
      else            v = 2.f*cw[(size_t)(128+h)*64 + col];
      Bp[(size_t)i*8 + j] = f2b(v);
    }
  } else {
    int i = (bi-6)*256 + tid;        // 6*8*64 = 3072
    int lane = i & 63; int cn = i >> 6; int c = cn >> 3; int n = cn & 7;
    #pragma unroll
    for(int j=0;j<8;j++){
      int k = c*32 + (lane>>4)*8 + j;
      int co = n*16 + (lane&15);
      int kt = k >> 6, ci = k & 63;
      Bp2[(size_t)i*8 + j] = f2b(w2[(size_t)co*192 + ci*3 + kt]);
    }
  }
}

// ---------------- temporal conv 1 + GLU -> bf16, flat [g][n][c] ----------------
__global__ void k_conv1(const float* __restrict__ X, const float* __restrict__ w1,
                        const float* __restrict__ b1, ushort_* __restrict__ t0){
  int wv = rfl_(blockIdx.x*4 + (threadIdx.x>>6));
  int lane = threadIdx.x & 63;
  int nb = wv % (N_/8); int bt = wv / (N_/8); int b = bt / T1_; int t = bt % T1_;
  int n0 = nb*8;
  const float* Xp = X + ((size_t)((b*T_ + t)*N_ + n0))*CIN_;
  float wp[6], wq[6];
  #pragma unroll
  for(int k=0;k<6;k++){
    wp[k] = w1[ lane      *6 + k];   // k = ci*3 + kt
    wq[k] = w1[(lane+H_)*6 + k];
  }
  float bp = b1[lane], bq = b1[lane+H_];
  ushort_* ob = t0 + ((size_t)bt*N_ + n0)*H_ + lane;
  #pragma unroll
  for(int j=0;j<8;j++){
    float yp = bp, yq = bq;
    #pragma unroll
    for(int kt=0;kt<KT_;kt++)
      #pragma unroll
      for(int ci=0;ci<CIN_;ci++){
        float x = Xp[kt*(N_*CIN_) + j*CIN_ + ci];
        yp += x * wp[ci*3+kt];
        yq += x * wq[ci*3+kt];
      }
    float xin = (lane < CIN_) ? Xp[2*(N_*CIN_) + j*CIN_ + lane] : 0.f;
    ob[j*H_] = f2b((yp + xin) * sigmoidf_(yq));
  }
}

// ---------------- SpMM flat: out = L zin. 8 graphs/wave, 16B gathers, XCD-swizzled ----
// lane -> graph g0+(lane>>3), channels (lane&7)*8..+8. Per edge: 8x128B txns (same as
// interleaved contiguous 1KB). Unrolled x4 for outstanding loads.
__global__ void k_spmm3(const ushort_* __restrict__ zin, ushort_* __restrict__ out,
                        const int* __restrict__ offs, const int2* __restrict__ epack){
  int lane = threadIdx.x & 63;
  int wv = threadIdx.x >> 6;
  int bid = blockIdx.x;                 // 14*512 = 7168
  int work = (bid & 7)*896 + (bid >> 3);
  int gg = work >> 9;                   // 0..13
  int dblk = work & 511;
  int d = dblk*4 + wv;
  int e0 = offs[d], e1 = offs[d+1];
  size_t lbase = (size_t)(gg*8 + (lane>>3))*N_*H_ + (lane&7)*8;
  const ushort_* zb = zin + lbase;
  float ac[8] = {};
  int i = e0;
  for(; i+3 < e1; i += 4){
    int2 ea = epack[i], eb = epack[i+1], ec = epack[i+2], ed = epack[i+3];
    u16x8 za = *(const u16x8*)(zb + (size_t)ea.x*H_);
    u16x8 zvb = *(const u16x8*)(zb + (size_t)eb.x*H_);
    u16x8 zc = *(const u16x8*)(zb + (size_t)ec.x*H_);
    u16x8 zd = *(const u16x8*)(zb + (size_t)ed.x*H_);
    float wa = __int_as_float(ea.y), wb = __int_as_float(eb.y);
    float wc = __int_as_float(ec.y), wd = __int_as_float(ed.y);
    #pragma unroll
    for(int j=0;j<8;j++)
      ac[j] += wa*b2f(za[j]) + wb*b2f(zvb[j]) + wc*b2f(zc[j]) + wd*b2f(zd[j]);
  }
  for(; i < e1; i++){
    int2 e = epack[i];
    float w = __int_as_float(e.y);
    u16x8 zv = *(const u16x8*)(zb + (size_t)e.x*H_);
    #pragma unroll
    for(int j=0;j<8;j++) ac[j] += w*b2f(zv[j]);
  }
  u16x8 ov;
  #pragma unroll
  for(int j=0;j<8;j++) ov[j] = f2b(ac[j]);
  *(u16x8*)(out + lbase + (size_t)d*H_) = ov;
}

// ---------------- cheb GEMM via MFMA (flat A, LDS-staged baked B) ----------------
// tg = relu(bias + t0*(W0-W2) + tx1*W1 + y2*(2W2))
__global__ __launch_bounds__(256) void k_cheb_mfma(
    const ushort_* __restrict__ t0, const ushort_* __restrict__ tx1,
    const ushort_* __restrict__ y2, const ushort_* __restrict__ Bp,
    const float* __restrict__ bias, ushort_* __restrict__ tg){
  __shared__ ushort_ lb[6*4*64*8];   // 24 KB
  int tid = threadIdx.x;
  #pragma unroll
  for(int i=0;i<6;i++)
    *(u16x8*)(lb + i*2048 + tid*8) = *(const u16x8*)(Bp + i*2048 + tid*8);
  __syncthreads();
  int lane = tid & 63;
  int wv = tid >> 6;
  int g = blockIdx.x >> 4;
  int row0 = (blockIdx.x & 15)*128 + wv*32;
  int ra = row0 + (lane&15);
  bf16x8 a[2][6];
  #pragma unroll
  for(int c=0;c<6;c++){
    const ushort_* s = (c>>1)==0 ? t0 : ((c>>1)==1 ? tx1 : y2);
    int eoff = (c&1)*32 + (lane>>4)*8;
    const ushort_* sb = s + (size_t)g*N_*H_ + eoff;
    a[0][c] = *(const bf16x8*)(sb + (size_t)ra*H_);
    a[1][c] = *(const bf16x8*)(sb + (size_t)(ra+16)*H_);
  }
  f32x4 acc[2][4] = {};
  #pragma unroll
  for(int c=0;c<6;c++){
    #pragma unroll
    for(int n=0;n<4;n++){
      bf16x8 bfr = *(const bf16x8*)(lb + ((c*4+n)*64 + lane)*8);
      acc[0][n] = __builtin_amdgcn_mfma_f32_16x16x32_bf16(a[0][c], bfr, acc[0][n], 0,0,0);
      acc[1][n] = __builtin_amdgcn_mfma_f32_16x16x32_bf16(a[1][c], bfr, acc[1][n], 0,0,0);
    }
  }
  #pragma unroll
  for(int rg=0; rg<2; rg++)
    #pragma unroll
    for(int n=0;n<4;n++){
      int col = n*16 + (lane&15);
      float bv = bias[col];
      #pragma unroll
      for(int r=0;r<4;r++){
        int row = row0 + rg*16 + (lane>>4)*4 + r;
        float v = fmaxf(acc[rg][n][r] + bv, 0.f);
        tg[(size_t)(g*N_+row)*H_ + col] = f2b(v);
      }
    }
}

// ---------------- conv2 via MFMA (LDS-staged B, 32 rows/wave) ----------------
__global__ __launch_bounds__(256) void k_conv2_mfma(
    const ushort_* __restrict__ tg, const ushort_* __restrict__ Bp2,
    const float* __restrict__ b2, float* __restrict__ out){
  __shared__ ushort_ lb[6*8*64*8];  // 48 KB
  int tid = threadIdx.x;
  #pragma unroll
  for(int i=0;i<12;i++)
    *(u16x8*)(lb + i*2048 + tid*8) = *(const u16x8*)(Bp2 + i*2048 + tid*8);
  __syncthreads();
  int lane = tid & 63;
  int wv = tid >> 6;
  int blk = blockIdx.x;          // 96*16
  int bt = blk >> 4; int nblk = blk & 15;
  int b = bt / T2_, t = bt % T2_;
  int n0 = nblk*128 + wv*32;
  const ushort_* base = tg + (size_t)(b*T1_ + t)*N_*H_;
  int ra = n0 + (lane&15);
  f32x4 acc[2][8] = {};
  #pragma unroll
  for(int c=0;c<6;c++){
    const ushort_* s = base + (size_t)(c>>1)*N_*H_;
    int eoff = (c&1)*32 + (lane>>4)*8;
    bf16x8 a0 = *(const bf16x8*)(s + (size_t)ra*H_ + eoff);
    bf16x8 a1 = *(const bf16x8*)(s + (size_t)(ra+16)*H_ + eoff);
    #pragma unroll
    for(int n=0;n<8;n++){
      bf16x8 bfr = *(const bf16x8*)(lb + ((c*8+n)*64 + lane)*8);
      acc[0][n] = __builtin_amdgcn_mfma_f32_16x16x32_bf16(a0, bfr, acc[0][n], 0,0,0);
      acc[1][n] = __builtin_amdgcn_mfma_f32_16x16x32_bf16(a1, bfr, acc[1][n], 0,0,0);
    }
  }
  const ushort_* xslab = base + (size_t)2*N_*H_;
  float* ob = out + (size_t)(b*T2_ + t)*N_*H_;
  #pragma unroll
  for(int rg=0;rg<2;rg++)
    #pragma unroll
    for(int n=0;n<4;n++){
      int col = n*16 + (lane&15);
      float bp = b2[col], bq = b2[col+COUT_];
      #pragma unroll
      for(int r=0;r<4;r++){
        int row = n0 + rg*16 + (lane>>4)*4 + r;
        float xin = b2f(xslab[(size_t)row*H_ + col]);
        float p = acc[rg][n][r] + bp + xin;
        float q = acc[rg][n+4][r] + bq;
        ob[(size_t)row*H_ + col] = p * sigmoidf_(q);
      }
    }
}

extern "C" void kernel_launch(void* const* d_in, const int* in_sizes, int n_in,
                              void* d_out, int out_size, void* d_ws, size_t ws_size,
                              hipStream_t stream){
  (void)in_sizes; (void)n_in; (void)out_size; (void)ws_size;
  const float* X  = (const float*)d_in[0];
  const int*   ei = (const int*)d_in[1];
  const float* ew = (const float*)d_in[2];
  const float* w1 = (const float*)d_in[3];
  const float* b1 = (const float*)d_in[4];
  const float* cw = (const float*)d_in[5];
  const float* cb = (const float*)d_in[6];
  const float* w2 = (const float*)d_in[7];
  const float* b2 = (const float*)d_in[8];
  float* out = (float*)d_out;

  char* ws = (char*)d_ws;
  const size_t BUF = (size_t)G_*N_*H_*sizeof(ushort_); // 29,360,128 B
  ushort_* t0  = (ushort_*)(ws);
  ushort_* tx1 = (ushort_*)(ws + BUF);
  ushort_* y2  = (ushort_*)(ws + 2*BUF);
  ushort_* tg  = (ushort_*)(ws + 3*BUF);
  char* sm = ws + 4*BUF;
  int*   offs  = (int*)  (sm);               // 8448
  int2*  epack = (int2*) (sm + 8448);        // 262144
  ushort_* Bp  = (ushort_*)(sm + 8448 + 262144);          // 24576
  ushort_* Bp2 = (ushort_*)(sm + 8448 + 262144 + 24576);  // 49152

  const int* src = ei;
  const int* dst = ei + E_;

  k_csr <<<1, 1024, 0, stream>>>(src, dst, ew, offs, epack);
  k_prep<<<18, 256, 0, stream>>>(cw, w2, Bp, Bp2);

  // stage 1: temporal conv1 + GLU -> t0 (bf16, flat)
  k_conv1<<<(G_*N_/8)/4, 256, 0, stream>>>(X, w1, b1, t0);

  // tx1 = L t0 ; y2 = L tx1
  k_spmm3<<<14*512, 256, 0, stream>>>(t0,  tx1, offs, epack);
  k_spmm3<<<14*512, 256, 0, stream>>>(tx1, y2,  offs, epack);

  // tg = relu(bias + t0*(W0-W2) + tx1*W1 + y2*(2W2))   (MFMA, LDS B)
  k_cheb_mfma<<<G_*16, 256, 0, stream>>>(t0, tx1, y2, Bp, cb, tg);

  // stage 3: temporal conv2 + GLU -> out   (MFMA, LDS B)
  k_conv2_mfma<<<(B_*T2_)*16, 256, 0, stream>>>(tg, Bp2, b2, out);
}

// Round 10
// 155.491 us; speedup vs baseline: 1.5933x; 1.3180x over previous
//
#include <hip/hip_runtime.h>
#include <cstdint>

#define B_ 8
#define T_ 16
#define N_ 2048
#define CIN_ 2
#define H_ 64
#define COUT_ 64
#define KT_ 3
#define E_ 32768
#define T1_ 14
#define T2_ 12
#define G_ (B_*T1_)   // 112 graphs

typedef __attribute__((ext_vector_type(8))) short bf16x8;
typedef __attribute__((ext_vector_type(4))) float f32x4;
typedef unsigned short ushort_;
typedef __attribute__((ext_vector_type(8))) unsigned short u16x8;

__device__ __forceinline__ float sigmoidf_(float x){ return 1.f/(1.f+expf(-x)); }
__device__ __forceinline__ int rfl_(int x){ return __builtin_amdgcn_readfirstlane(x); }

__device__ __forceinline__ ushort_ f2b(float x){
  union {float f; uint32_t u;} v; v.f = x;
  uint32_t r = (v.u + 0x7FFFu + ((v.u>>16)&1u)) >> 16;
  return (ushort_)r;
}
__device__ __forceinline__ float b2f(ushort_ x){
  union {uint32_t u; float f;} v; v.u = ((uint32_t)x)<<16;
  return v.f;
}

// ---------------- CSR build (parallel mini-chain) ----------------
__global__ void k_zero(float* __restrict__ deg, int* __restrict__ cnt, int* __restrict__ fillc){
  int i = blockIdx.x*blockDim.x + threadIdx.x;
  if(i < N_){ deg[i] = 0.f; cnt[i] = 0; fillc[i] = 0; }
}

__global__ void k_deg_cnt(const int* __restrict__ src, const int* __restrict__ dst,
                          const float* __restrict__ ew, float* deg, int* cnt){
  int e = blockIdx.x*blockDim.x + threadIdx.x;
  if(e >= E_) return;
  int s = src[e], d = dst[e];
  float w = (s==d) ? 0.f : ew[e];
  atomicAdd(&deg[s], w);
  atomicAdd(&cnt[d], 1);
}

// single block: exclusive scan of cnt -> offs, and deg -> dis (in place over deg)
__global__ void k_scan_dis(const int* __restrict__ cnt, int* __restrict__ offs,
                           float* __restrict__ deg){
  __shared__ int sums[256];
  int tid = threadIdx.x;
  int base = tid*8;
  int loc[8]; int s = 0;
  #pragma unroll
  for(int j=0;j<8;j++){ loc[j]=s; s += cnt[base+j]; }
  sums[tid] = s; __syncthreads();
  for(int ofs=1; ofs<256; ofs<<=1){
    int t = (tid>=ofs) ? sums[tid-ofs] : 0;
    __syncthreads();
    sums[tid] += t;
    __syncthreads();
  }
  int ebase = (tid==0) ? 0 : sums[tid-1];
  #pragma unroll
  for(int j=0;j<8;j++) offs[base+j] = ebase + loc[j];
  if(tid==255) offs[N_] = sums[255];
  #pragma unroll
  for(int j=0;j<8;j++){
    float dg = deg[base+j];
    deg[base+j] = dg > 0.f ? rsqrtf(dg) : 0.f;
  }
}

__global__ void k_fill(const int* __restrict__ src, const int* __restrict__ dst,
                       const float* __restrict__ ew, const float* __restrict__ dis,
                       const int* __restrict__ offs, int* fillc,
                       int2* __restrict__ epack){
  int e = blockIdx.x*blockDim.x + threadIdx.x;
  if(e >= E_) return;
  int s = src[e], d = dst[e];
  float w = (s==d) ? 0.f : ew[e];
  float wn = -dis[s]*w*dis[d];
  int pos = offs[d] + atomicAdd(&fillc[d], 1);
  epack[pos] = make_int2(s, __float_as_int(wn));
}

// ---- weight prepack (merged): blocks 0..5 cheb (baked W0-W2|W1|2W2), 6..17 conv2 ----
__global__ void k_prep(const float* __restrict__ cw, const float* __restrict__ w2,
                       ushort_* __restrict__ Bp, ushort_* __restrict__ Bp2){
  int bi = blockIdx.x; int tid = threadIdx.x;
  if(bi < 6){
    int i = bi*256 + tid;            // 6*4*64 = 1536
    int lane = i & 63; int cn = i >> 6; int c = cn >> 2; int n = cn & 3;
    #pragma unroll
    for(int j=0;j<8;j++){
      int k = c*32 + (lane>>4)*8 + j;   // 0..191
      int h = k & 63; int m = k >> 6;
      int col = n*16 + (lane&15);
      float v;
      if(m == 0)      v = cw[(size_t)h*64 + col] - cw[(size_t)(128+h)*64 + col];
      else if(m == 1) v = cw[(size_t)(64+h)*64 + col];
      else            v = 2.f*cw[(size_t)(128+h)*64 + col];
      Bp[(size_t)i*8 + j] = f2b(v);
    }
  } else {
    int i = (bi-6)*256 + tid;        // 6*8*64 = 3072
    int lane = i & 63; int cn = i >> 6; int c = cn >> 3; int n = cn & 7;
    #pragma unroll
    for(int j=0;j<8;j++){
      int k = c*32 + (lane>>4)*8 + j;
      int co = n*16 + (lane&15);
      int kt = k >> 6, ci = k & 63;
      Bp2[(size_t)i*8 + j] = f2b(w2[(size_t)co*192 + ci*3 + kt]);
    }
  }
}

// ---------------- temporal conv 1 + GLU -> bf16, flat [g][n][c] ----------------
__global__ void k_conv1(const float* __restrict__ X, const float* __restrict__ w1,
                        const float* __restrict__ b1, ushort_* __restrict__ t0){
  int wv = rfl_(blockIdx.x*4 + (threadIdx.x>>6));
  int lane = threadIdx.x & 63;
  int nb = wv % (N_/8); int bt = wv / (N_/8); int b = bt / T1_; int t = bt % T1_;
  int n0 = nb*8;
  const float* Xp = X + ((size_t)((b*T_ + t)*N_ + n0))*CIN_;
  float wp[6], wq[6];
  #pragma unroll
  for(int k=0;k<6;k++){
    wp[k] = w1[ lane      *6 + k];   // k = ci*3 + kt
    wq[k] = w1[(lane+H_)*6 + k];
  }
  float bp = b1[lane], bq = b1[lane+H_];
  ushort_* ob = t0 + ((size_t)bt*N_ + n0)*H_ + lane;
  #pragma unroll
  for(int j=0;j<8;j++){
    float yp = bp, yq = bq;
    #pragma unroll
    for(int kt=0;kt<KT_;kt++)
      #pragma unroll
      for(int ci=0;ci<CIN_;ci++){
        float x = Xp[kt*(N_*CIN_) + j*CIN_ + ci];
        yp += x * wp[ci*3+kt];
        yq += x * wq[ci*3+kt];
      }
    float xin = (lane < CIN_) ? Xp[2*(N_*CIN_) + j*CIN_ + lane] : 0.f;
    ob[j*H_] = f2b((yp + xin) * sigmoidf_(yq));
  }
}

// ---------------- SpMM flat: out = L zin. 8 graphs/wave, 16B gathers, XCD-swizzled ----
__global__ void k_spmm3(const ushort_* __restrict__ zin, ushort_* __restrict__ out,
                        const int* __restrict__ offs, const int2* __restrict__ epack){
  int lane = threadIdx.x & 63;
  int wv = threadIdx.x >> 6;
  int bid = blockIdx.x;                 // 14*512 = 7168
  int work = (bid & 7)*896 + (bid >> 3);
  int gg = work >> 9;                   // 0..13
  int dblk = work & 511;
  int d = dblk*4 + wv;
  int e0 = offs[d], e1 = offs[d+1];
  size_t lbase = (size_t)(gg*8 + (lane>>3))*N_*H_ + (lane&7)*8;
  const ushort_* zb = zin + lbase;
  float ac[8] = {};
  int i = e0;
  for(; i+3 < e1; i += 4){
    int2 ea = epack[i], eb = epack[i+1], ec = epack[i+2], ed = epack[i+3];
    u16x8 za = *(const u16x8*)(zb + (size_t)ea.x*H_);
    u16x8 zvb = *(const u16x8*)(zb + (size_t)eb.x*H_);
    u16x8 zc = *(const u16x8*)(zb + (size_t)ec.x*H_);
    u16x8 zd = *(const u16x8*)(zb + (size_t)ed.x*H_);
    float wa = __int_as_float(ea.y), wb = __int_as_float(eb.y);
    float wc = __int_as_float(ec.y), wd = __int_as_float(ed.y);
    #pragma unroll
    for(int j=0;j<8;j++)
      ac[j] += wa*b2f(za[j]) + wb*b2f(zvb[j]) + wc*b2f(zc[j]) + wd*b2f(zd[j]);
  }
  for(; i < e1; i++){
    int2 e = epack[i];
    float w = __int_as_float(e.y);
    u16x8 zv = *(const u16x8*)(zb + (size_t)e.x*H_);
    #pragma unroll
    for(int j=0;j<8;j++) ac[j] += w*b2f(zv[j]);
  }
  u16x8 ov;
  #pragma unroll
  for(int j=0;j<8;j++) ov[j] = f2b(ac[j]);
  *(u16x8*)(out + lbase + (size_t)d*H_) = ov;
}

// ---------------- cheb GEMM via MFMA (flat A, LDS-staged baked B) ----------------
// tg = relu(bias + t0*(W0-W2) + tx1*W1 + y2*(2W2))
__global__ __launch_bounds__(256) void k_cheb_mfma(
    const ushort_* __restrict__ t0, const ushort_* __restrict__ tx1,
    const ushort_* __restrict__ y2, const ushort_* __restrict__ Bp,
    const float* __restrict__ bias, ushort_* __restrict__ tg){
  __shared__ ushort_ lb[6*4*64*8];   // 24 KB
  int tid = threadIdx.x;
  #pragma unroll
  for(int i=0;i<6;i++)
    *(u16x8*)(lb + i*2048 + tid*8) = *(const u16x8*)(Bp + i*2048 + tid*8);
  __syncthreads();
  int lane = tid & 63;
  int wv = tid >> 6;
  int g = blockIdx.x >> 4;
  int row0 = (blockIdx.x & 15)*128 + wv*32;
  int ra = row0 + (lane&15);
  bf16x8 a[2][6];
  #pragma unroll
  for(int c=0;c<6;c++){
    const ushort_* s = (c>>1)==0 ? t0 : ((c>>1)==1 ? tx1 : y2);
    int eoff = (c&1)*32 + (lane>>4)*8;
    const ushort_* sb = s + (size_t)g*N_*H_ + eoff;
    a[0][c] = *(const bf16x8*)(sb + (size_t)ra*H_);
    a[1][c] = *(const bf16x8*)(sb + (size_t)(ra+16)*H_);
  }
  f32x4 acc[2][4] = {};
  #pragma unroll
  for(int c=0;c<6;c++){
    #pragma unroll
    for(int n=0;n<4;n++){
      bf16x8 bfr = *(const bf16x8*)(lb + ((c*4+n)*64 + lane)*8);
      acc[0][n] = __builtin_amdgcn_mfma_f32_16x16x32_bf16(a[0][c], bfr, acc[0][n], 0,0,0);
      acc[1][n] = __builtin_amdgcn_mfma_f32_16x16x32_bf16(a[1][c], bfr, acc[1][n], 0,0,0);
    }
  }
  #pragma unroll
  for(int rg=0; rg<2; rg++)
    #pragma unroll
    for(int n=0;n<4;n++){
      int col = n*16 + (lane&15);
      float bv = bias[col];
      #pragma unroll
      for(int r=0;r<4;r++){
        int row = row0 + rg*16 + (lane>>4)*4 + r;
        float v = fmaxf(acc[rg][n][r] + bv, 0.f);
        tg[(size_t)(g*N_+row)*H_ + col] = f2b(v);
      }
    }
}

// ---------------- conv2 via MFMA (LDS-staged B, 32 rows/wave) ----------------
__global__ __launch_bounds__(256) void k_conv2_mfma(
    const ushort_* __restrict__ tg, const ushort_* __restrict__ Bp2,
    const float* __restrict__ b2, float* __restrict__ out){
  __shared__ ushort_ lb[6*8*64*8];  // 48 KB
  int tid = threadIdx.x;
  #pragma unroll
  for(int i=0;i<12;i++)
    *(u16x8*)(lb + i*2048 + tid*8) = *(const u16x8*)(Bp2 + i*2048 + tid*8);
  __syncthreads();
  int lane = tid & 63;
  int wv = tid >> 6;
  int blk = blockIdx.x;          // 96*16
  int bt = blk >> 4; int nblk = blk & 15;
  int b = bt / T2_, t = bt % T2_;
  int n0 = nblk*128 + wv*32;
  const ushort_* base = tg + (size_t)(b*T1_ + t)*N_*H_;
  int ra = n0 + (lane&15);
  f32x4 acc[2][8] = {};
  #pragma unroll
  for(int c=0;c<6;c++){
    const ushort_* s = base + (size_t)(c>>1)*N_*H_;
    int eoff = (c&1)*32 + (lane>>4)*8;
    bf16x8 a0 = *(const bf16x8*)(s + (size_t)ra*H_ + eoff);
    bf16x8 a1 = *(const bf16x8*)(s + (size_t)(ra+16)*H_ + eoff);
    #pragma unroll
    for(int n=0;n<8;n++){
      bf16x8 bfr = *(const bf16x8*)(lb + ((c*8+n)*64 + lane)*8);
      acc[0][n] = __builtin_amdgcn_mfma_f32_16x16x32_bf16(a0, bfr, acc[0][n], 0,0,0);
      acc[1][n] = __builtin_amdgcn_mfma_f32_16x16x32_bf16(a1, bfr, acc[1][n], 0,0,0);
    }
  }
  const ushort_* xslab = base + (size_t)2*N_*H_;
  float* ob = out + (size_t)(b*T2_ + t)*N_*H_;
  #pragma unroll
  for(int rg=0;rg<2;rg++)
    #pragma unroll
    for(int n=0;n<4;n++){
      int col = n*16 + (lane&15);
      float bp = b2[col], bq = b2[col+COUT_];
      #pragma unroll
      for(int r=0;r<4;r++){
        int row = n0 + rg*16 + (lane>>4)*4 + r;
        float xin = b2f(xslab[(size_t)row*H_ + col]);
        float p = acc[rg][n][r] + bp + xin;
        float q = acc[rg][n+4][r] + bq;
        ob[(size_t)row*H_ + col] = p * sigmoidf_(q);
      }
    }
}

extern "C" void kernel_launch(void* const* d_in, const int* in_sizes, int n_in,
                              void* d_out, int out_size, void* d_ws, size_t ws_size,
                              hipStream_t stream){
  (void)in_sizes; (void)n_in; (void)out_size; (void)ws_size;
  const float* X  = (const float*)d_in[0];
  const int*   ei = (const int*)d_in[1];
  const float* ew = (const float*)d_in[2];
  const float* w1 = (const float*)d_in[3];
  const float* b1 = (const float*)d_in[4];
  const float* cw = (const float*)d_in[5];
  const float* cb = (const float*)d_in[6];
  const float* w2 = (const float*)d_in[7];
  const float* b2 = (const float*)d_in[8];
  float* out = (float*)d_out;

  char* ws = (char*)d_ws;
  const size_t BUF = (size_t)G_*N_*H_*sizeof(ushort_); // 29,360,128 B
  ushort_* t0  = (ushort_*)(ws);
  ushort_* tx1 = (ushort_*)(ws + BUF);
  ushort_* y2  = (ushort_*)(ws + 2*BUF);
  ushort_* tg  = (ushort_*)(ws + 3*BUF);
  char* sm = ws + 4*BUF;
  float* deg   = (float*)(sm);               // 8192 (-> dis in place)
  int*   cnt   = (int*)  (sm + 8192);        // 8192
  int*   fillc = (int*)  (sm + 16384);       // 8192
  int*   offs  = (int*)  (sm + 24576);       // 8448
  int2*  epack = (int2*) (sm + 33024);       // 262144
  ushort_* Bp  = (ushort_*)(sm + 33024 + 262144);          // 24576
  ushort_* Bp2 = (ushort_*)(sm + 33024 + 262144 + 24576);  // 49152

  const int* src = ei;
  const int* dst = ei + E_;

  k_zero    <<<N_/256, 256, 0, stream>>>(deg, cnt, fillc);
  k_deg_cnt <<<E_/256, 256, 0, stream>>>(src, dst, ew, deg, cnt);
  k_scan_dis<<<1,      256, 0, stream>>>(cnt, offs, deg);
  k_fill    <<<E_/256, 256, 0, stream>>>(src, dst, ew, deg, offs, fillc, epack);
  k_prep    <<<18,     256, 0, stream>>>(cw, w2, Bp, Bp2);

  // stage 1: temporal conv1 + GLU -> t0 (bf16, flat)
  k_conv1<<<(G_*N_/8)/4, 256, 0, stream>>>(X, w1, b1, t0);

  // tx1 = L t0 ; y2 = L tx1
  k_spmm3<<<14*512, 256, 0, stream>>>(t0,  tx1, offs, epack);
  k_spmm3<<<14*512, 256, 0, stream>>>(tx1, y2,  offs, epack);

  // tg = relu(bias + t0*(W0-W2) + tx1*W1 + y2*(2W2))   (MFMA, LDS B)
  k_cheb_mfma<<<G_*16, 256, 0, stream>>>(t0, tx1, y2, Bp, cb, tg);

  // stage 3: temporal conv2 + GLU -> out   (MFMA, LDS B)
  k_conv2_mfma<<<(B_*T2_)*16, 256, 0, stream>>>(tg, Bp2, b2, out);
}

// Round 11
// 147.408 us; speedup vs baseline: 1.6807x; 1.0548x over previous
//
#include <hip/hip_runtime.h>
#include <cstdint>

#define B_ 8
#define T_ 16
#define N_ 2048
#define CIN_ 2
#define H_ 64
#define COUT_ 64
#define KT_ 3
#define E_ 32768
#define T1_ 14
#define T2_ 12
#define G_ (B_*T1_)   // 112 graphs

typedef __attribute__((ext_vector_type(8))) short bf16x8;
typedef __attribute__((ext_vector_type(4))) float f32x4;
typedef unsigned short ushort_;
typedef __attribute__((ext_vector_type(8))) unsigned short u16x8;

__device__ __forceinline__ float sigmoidf_(float x){ return 1.f/(1.f+expf(-x)); }
__device__ __forceinline__ int rfl_(int x){ return __builtin_amdgcn_readfirstlane(x); }

__device__ __forceinline__ ushort_ f2b(float x){
  union {float f; uint32_t u;} v; v.f = x;
  uint32_t r = (v.u + 0x7FFFu + ((v.u>>16)&1u)) >> 16;
  return (ushort_)r;
}
__device__ __forceinline__ float b2f(ushort_ x){
  union {uint32_t u; float f;} v; v.u = ((uint32_t)x)<<16;
  return v.f;
}

// ---------------- setup: weight prepack (blocks 0..17) + zero (blocks 18..25) ----------------
__global__ void k_setup(const float* __restrict__ cw, const float* __restrict__ w2,
                        ushort_* __restrict__ Bp, ushort_* __restrict__ Bp2,
                        float* __restrict__ deg, int* __restrict__ cnt,
                        int* __restrict__ fillc){
  int bi = blockIdx.x; int tid = threadIdx.x;
  if(bi < 6){
    int i = bi*256 + tid;            // 6*4*64 = 1536
    int lane = i & 63; int cn = i >> 6; int c = cn >> 2; int n = cn & 3;
    #pragma unroll
    for(int j=0;j<8;j++){
      int k = c*32 + (lane>>4)*8 + j;   // 0..191
      int h = k & 63; int m = k >> 6;
      int col = n*16 + (lane&15);
      float v;
      if(m == 0)      v = cw[(size_t)h*64 + col] - cw[(size_t)(128+h)*64 + col];
      else if(m == 1) v = cw[(size_t)(64+h)*64 + col];
      else            v = 2.f*cw[(size_t)(128+h)*64 + col];
      Bp[(size_t)i*8 + j] = f2b(v);
    }
  } else if(bi < 18){
    int i = (bi-6)*256 + tid;        // 6*8*64 = 3072
    int lane = i & 63; int cn = i >> 6; int c = cn >> 3; int n = cn & 7;
    #pragma unroll
    for(int j=0;j<8;j++){
      int k = c*32 + (lane>>4)*8 + j;
      int co = n*16 + (lane&15);
      int kt = k >> 6, ci = k & 63;
      Bp2[(size_t)i*8 + j] = f2b(w2[(size_t)co*192 + ci*3 + kt]);
    }
  } else {
    int i = (bi-18)*256 + tid;
    if(i < N_){ deg[i] = 0.f; cnt[i] = 0; fillc[i] = 0; }
  }
}

__global__ void k_deg_cnt(const int* __restrict__ src, const int* __restrict__ dst,
                          const float* __restrict__ ew, float* deg, int* cnt){
  int e = blockIdx.x*blockDim.x + threadIdx.x;
  if(e >= E_) return;
  int s = src[e], d = dst[e];
  float w = (s==d) ? 0.f : ew[e];
  atomicAdd(&deg[s], w);
  atomicAdd(&cnt[d], 1);
}

// single block: exclusive scan of cnt -> offs, and deg -> dis (in place over deg)
__global__ void k_scan_dis(const int* __restrict__ cnt, int* __restrict__ offs,
                           float* __restrict__ deg){
  __shared__ int sums[256];
  int tid = threadIdx.x;
  int base = tid*8;
  int loc[8]; int s = 0;
  #pragma unroll
  for(int j=0;j<8;j++){ loc[j]=s; s += cnt[base+j]; }
  sums[tid] = s; __syncthreads();
  for(int ofs=1; ofs<256; ofs<<=1){
    int t = (tid>=ofs) ? sums[tid-ofs] : 0;
    __syncthreads();
    sums[tid] += t;
    __syncthreads();
  }
  int ebase = (tid==0) ? 0 : sums[tid-1];
  #pragma unroll
  for(int j=0;j<8;j++) offs[base+j] = ebase + loc[j];
  if(tid==255) offs[N_] = sums[255];
  #pragma unroll
  for(int j=0;j<8;j++){
    float dg = deg[base+j];
    deg[base+j] = dg > 0.f ? rsqrtf(dg) : 0.f;
  }
}

// ---------------- fill (blocks 0..127) + temporal conv1 (blocks 128..) ----------------
__global__ void k_fill_conv1(const int* __restrict__ src, const int* __restrict__ dst,
                             const float* __restrict__ ew, const float* __restrict__ dis,
                             const int* __restrict__ offs, int* fillc,
                             int2* __restrict__ epack,
                             const float* __restrict__ X, const float* __restrict__ w1,
                             const float* __restrict__ b1, ushort_* __restrict__ t0){
  int bi = blockIdx.x;
  if(bi < 128){
    int e = bi*256 + threadIdx.x;
    if(e >= E_) return;
    int s = src[e], d = dst[e];
    float w = (s==d) ? 0.f : ew[e];
    float wn = -dis[s]*w*dis[d];
    int pos = offs[d] + atomicAdd(&fillc[d], 1);
    epack[pos] = make_int2(s, __float_as_int(wn));
    return;
  }
  int wv = rfl_((bi-128)*4 + (threadIdx.x>>6));
  int lane = threadIdx.x & 63;
  int nb = wv % (N_/8); int bt = wv / (N_/8); int b = bt / T1_; int t = bt % T1_;
  int n0 = nb*8;
  const float* Xp = X + ((size_t)((b*T_ + t)*N_ + n0))*CIN_;
  float wp[6], wq[6];
  #pragma unroll
  for(int k=0;k<6;k++){
    wp[k] = w1[ lane      *6 + k];   // k = ci*3 + kt
    wq[k] = w1[(lane+H_)*6 + k];
  }
  float bp = b1[lane], bq = b1[lane+H_];
  ushort_* ob = t0 + ((size_t)bt*N_ + n0)*H_ + lane;
  #pragma unroll
  for(int j=0;j<8;j++){
    float yp = bp, yq = bq;
    #pragma unroll
    for(int kt=0;kt<KT_;kt++)
      #pragma unroll
      for(int ci=0;ci<CIN_;ci++){
        float x = Xp[kt*(N_*CIN_) + j*CIN_ + ci];
        yp += x * wp[ci*3+kt];
        yq += x * wq[ci*3+kt];
      }
    float xin = (lane < CIN_) ? Xp[2*(N_*CIN_) + j*CIN_ + lane] : 0.f;
    ob[j*H_] = f2b((yp + xin) * sigmoidf_(yq));
  }
}

// ---------------- SpMM flat: out = L zin. 8 graphs/wave, 16B gathers, XCD-swizzled ----
// unroll 8 / 4 / 1 for outstanding gather depth
__global__ void k_spmm3(const ushort_* __restrict__ zin, ushort_* __restrict__ out,
                        const int* __restrict__ offs, const int2* __restrict__ epack){
  int lane = threadIdx.x & 63;
  int wv = threadIdx.x >> 6;
  int bid = blockIdx.x;                 // 14*512 = 7168
  int work = (bid & 7)*896 + (bid >> 3);
  int gg = work >> 9;                   // 0..13
  int dblk = work & 511;
  int d = dblk*4 + wv;
  int e0 = offs[d], e1 = offs[d+1];
  size_t lbase = (size_t)(gg*8 + (lane>>3))*N_*H_ + (lane&7)*8;
  const ushort_* zb = zin + lbase;
  float ac[8] = {};
  int i = e0;
  for(; i+7 < e1; i += 8){
    int2 ee[8]; u16x8 zz[8];
    #pragma unroll
    for(int u=0;u<8;u++) ee[u] = epack[i+u];
    #pragma unroll
    for(int u=0;u<8;u++) zz[u] = *(const u16x8*)(zb + (size_t)ee[u].x*H_);
    #pragma unroll
    for(int u=0;u<8;u++){
      float w = __int_as_float(ee[u].y);
      #pragma unroll
      for(int j=0;j<8;j++) ac[j] += w*b2f(zz[u][j]);
    }
  }
  for(; i+3 < e1; i += 4){
    int2 ee[4]; u16x8 zz[4];
    #pragma unroll
    for(int u=0;u<4;u++) ee[u] = epack[i+u];
    #pragma unroll
    for(int u=0;u<4;u++) zz[u] = *(const u16x8*)(zb + (size_t)ee[u].x*H_);
    #pragma unroll
    for(int u=0;u<4;u++){
      float w = __int_as_float(ee[u].y);
      #pragma unroll
      for(int j=0;j<8;j++) ac[j] += w*b2f(zz[u][j]);
    }
  }
  for(; i < e1; i++){
    int2 e = epack[i];
    float w = __int_as_float(e.y);
    u16x8 zv = *(const u16x8*)(zb + (size_t)e.x*H_);
    #pragma unroll
    for(int j=0;j<8;j++) ac[j] += w*b2f(zv[j]);
  }
  u16x8 ov;
  #pragma unroll
  for(int j=0;j<8;j++) ov[j] = f2b(ac[j]);
  *(u16x8*)(out + lbase + (size_t)d*H_) = ov;
}

// ---------------- cheb GEMM via MFMA (flat A, LDS-staged baked B) ----------------
// tg = relu(bias + t0*(W0-W2) + tx1*W1 + y2*(2W2))
__global__ __launch_bounds__(256) void k_cheb_mfma(
    const ushort_* __restrict__ t0, const ushort_* __restrict__ tx1,
    const ushort_* __restrict__ y2, const ushort_* __restrict__ Bp,
    const float* __restrict__ bias, ushort_* __restrict__ tg){
  __shared__ ushort_ lb[6*4*64*8];   // 24 KB
  int tid = threadIdx.x;
  #pragma unroll
  for(int i=0;i<6;i++)
    *(u16x8*)(lb + i*2048 + tid*8) = *(const u16x8*)(Bp + i*2048 + tid*8);
  __syncthreads();
  int lane = tid & 63;
  int wv = tid >> 6;
  int g = blockIdx.x >> 4;
  int row0 = (blockIdx.x & 15)*128 + wv*32;
  int ra = row0 + (lane&15);
  bf16x8 a[2][6];
  #pragma unroll
  for(int c=0;c<6;c++){
    const ushort_* s = (c>>1)==0 ? t0 : ((c>>1)==1 ? tx1 : y2);
    int eoff = (c&1)*32 + (lane>>4)*8;
    const ushort_* sb = s + (size_t)g*N_*H_ + eoff;
    a[0][c] = *(const bf16x8*)(sb + (size_t)ra*H_);
    a[1][c] = *(const bf16x8*)(sb + (size_t)(ra+16)*H_);
  }
  f32x4 acc[2][4] = {};
  #pragma unroll
  for(int c=0;c<6;c++){
    #pragma unroll
    for(int n=0;n<4;n++){
      bf16x8 bfr = *(const bf16x8*)(lb + ((c*4+n)*64 + lane)*8);
      acc[0][n] = __builtin_amdgcn_mfma_f32_16x16x32_bf16(a[0][c], bfr, acc[0][n], 0,0,0);
      acc[1][n] = __builtin_amdgcn_mfma_f32_16x16x32_bf16(a[1][c], bfr, acc[1][n], 0,0,0);
    }
  }
  #pragma unroll
  for(int rg=0; rg<2; rg++)
    #pragma unroll
    for(int n=0;n<4;n++){
      int col = n*16 + (lane&15);
      float bv = bias[col];
      #pragma unroll
      for(int r=0;r<4;r++){
        int row = row0 + rg*16 + (lane>>4)*4 + r;
        float v = fmaxf(acc[rg][n][r] + bv, 0.f);
        tg[(size_t)(g*N_+row)*H_ + col] = f2b(v);
      }
    }
}

// ---------------- conv2 via MFMA (LDS-staged B, 32 rows/wave) ----------------
__global__ __launch_bounds__(256) void k_conv2_mfma(
    const ushort_* __restrict__ tg, const ushort_* __restrict__ Bp2,
    const float* __restrict__ b2, float* __restrict__ out){
  __shared__ ushort_ lb[6*8*64*8];  // 48 KB
  int tid = threadIdx.x;
  #pragma unroll
  for(int i=0;i<12;i++)
    *(u16x8*)(lb + i*2048 + tid*8) = *(const u16x8*)(Bp2 + i*2048 + tid*8);
  __syncthreads();
  int lane = tid & 63;
  int wv = tid >> 6;
  int blk = blockIdx.x;          // 96*16
  int bt = blk >> 4; int nblk = blk & 15;
  int b = bt / T2_, t = bt % T2_;
  int n0 = nblk*128 + wv*32;
  const ushort_* base = tg + (size_t)(b*T1_ + t)*N_*H_;
  int ra = n0 + (lane&15);
  f32x4 acc[2][8] = {};
  #pragma unroll
  for(int c=0;c<6;c++){
    const ushort_* s = base + (size_t)(c>>1)*N_*H_;
    int eoff = (c&1)*32 + (lane>>4)*8;
    bf16x8 a0 = *(const bf16x8*)(s + (size_t)ra*H_ + eoff);
    bf16x8 a1 = *(const bf16x8*)(s + (size_t)(ra+16)*H_ + eoff);
    #pragma unroll
    for(int n=0;n<8;n++){
      bf16x8 bfr = *(const bf16x8*)(lb + ((c*8+n)*64 + lane)*8);
      acc[0][n] = __builtin_amdgcn_mfma_f32_16x16x32_bf16(a0, bfr, acc[0][n], 0,0,0);
      acc[1][n] = __builtin_amdgcn_mfma_f32_16x16x32_bf16(a1, bfr, acc[1][n], 0,0,0);
    }
  }
  const ushort_* xslab = base + (size_t)2*N_*H_;
  float* ob = out + (size_t)(b*T2_ + t)*N_*H_;
  #pragma unroll
  for(int rg=0;rg<2;rg++)
    #pragma unroll
    for(int n=0;n<4;n++){
      int col = n*16 + (lane&15);
      float bp = b2[col], bq = b2[col+COUT_];
      #pragma unroll
      for(int r=0;r<4;r++){
        int row = n0 + rg*16 + (lane>>4)*4 + r;
        float xin = b2f(xslab[(size_t)row*H_ + col]);
        float p = acc[rg][n][r] + bp + xin;
        float q = acc[rg][n+4][r] + bq;
        ob[(size_t)row*H_ + col] = p * sigmoidf_(q);
      }
    }
}

extern "C" void kernel_launch(void* const* d_in, const int* in_sizes, int n_in,
                              void* d_out, int out_size, void* d_ws, size_t ws_size,
                              hipStream_t stream){
  (void)in_sizes; (void)n_in; (void)out_size; (void)ws_size;
  const float* X  = (const float*)d_in[0];
  const int*   ei = (const int*)d_in[1];
  const float* ew = (const float*)d_in[2];
  const float* w1 = (const float*)d_in[3];
  const float* b1 = (const float*)d_in[4];
  const float* cw = (const float*)d_in[5];
  const float* cb = (const float*)d_in[6];
  const float* w2 = (const float*)d_in[7];
  const float* b2 = (const float*)d_in[8];
  float* out = (float*)d_out;

  char* ws = (char*)d_ws;
  const size_t BUF = (size_t)G_*N_*H_*sizeof(ushort_); // 29,360,128 B
  ushort_* t0  = (ushort_*)(ws);
  ushort_* tx1 = (ushort_*)(ws + BUF);
  ushort_* y2  = (ushort_*)(ws + 2*BUF);
  ushort_* tg  = (ushort_*)(ws + 3*BUF);
  char* sm = ws + 4*BUF;
  float* deg   = (float*)(sm);               // 8192 (-> dis in place)
  int*   cnt   = (int*)  (sm + 8192);        // 8192
  int*   fillc = (int*)  (sm + 16384);       // 8192
  int*   offs  = (int*)  (sm + 24576);       // 8448
  int2*  epack = (int2*) (sm + 33024);       // 262144
  ushort_* Bp  = (ushort_*)(sm + 33024 + 262144);          // 24576
  ushort_* Bp2 = (ushort_*)(sm + 33024 + 262144 + 24576);  // 49152

  const int* src = ei;
  const int* dst = ei + E_;

  k_setup   <<<26,     256, 0, stream>>>(cw, w2, Bp, Bp2, deg, cnt, fillc);
  k_deg_cnt <<<E_/256, 256, 0, stream>>>(src, dst, ew, deg, cnt);
  k_scan_dis<<<1,      256, 0, stream>>>(cnt, offs, deg);

  // CSR fill (blocks 0..127) + temporal conv1 (blocks 128..) in one launch
  k_fill_conv1<<<128 + (G_*N_/8)/4, 256, 0, stream>>>(
      src, dst, ew, deg, offs, fillc, epack, X, w1, b1, t0);

  // tx1 = L t0 ; y2 = L tx1
  k_spmm3<<<14*512, 256, 0, stream>>>(t0,  tx1, offs, epack);
  k_spmm3<<<14*512, 256, 0, stream>>>(tx1, y2,  offs, epack);

  // tg = relu(bias + t0*(W0-W2) + tx1*W1 + y2*(2W2))   (MFMA, LDS B)
  k_cheb_mfma<<<G_*16, 256, 0, stream>>>(t0, tx1, y2, Bp, cb, tg);

  // stage 3: temporal conv2 + GLU -> out   (MFMA, LDS B)
  k_conv2_mfma<<<(B_*T2_)*16, 256, 0, stream>>>(tg, Bp2, b2, out);
}